// Round 2
// baseline (395.695 us; speedup 1.0000x reference)
//
#include <hip/hip_runtime.h>
#include <stdint.h>

// Problem constants (fixed by the reference)
#define BB 4
#define TT 2048
#define CC 1024
#define HH 16
#define DD 64
#define MM (BB*TT)   // 8192 rows

typedef __bf16 bf16x8 __attribute__((ext_vector_type(8)));
typedef float  f32x4  __attribute__((ext_vector_type(4)));

__device__ __forceinline__ unsigned short f2bf(float f) {
  __bf16 h = (__bf16)f;                  // compiler emits v_cvt (packs when possible)
  union { __bf16 h; unsigned short u; } c; c.h = h;
  return c.u;
}

// async global->LDS, 16B per lane; LDS dest must be wave-uniform base (HW adds lane*16)
__device__ __forceinline__ void glds16(const void* g, void* l) {
  __builtin_amdgcn_global_load_lds((const __attribute__((address_space(1))) void*)g,
                                   (__attribute__((address_space(3))) void*)l,
                                   16, 0, 0);
}

// XCD-aware chunked swizzle (bijective; requires nwg % 8 == 0)
__device__ __forceinline__ int xcd_swz(int bid, int nwg) {
  if (nwg & 7) return bid;
  return (bid & 7) * (nwg >> 3) + (bid >> 3);
}

// ---------------- fp32 -> bf16 bulk convert ----------------
typedef unsigned short u16x8 __attribute__((ext_vector_type(8)));
__global__ void f32_to_bf16_kn(const float* __restrict__ in,
                               unsigned short* __restrict__ out, int n) {
  int i = (blockIdx.x * blockDim.x + threadIdx.x) * 8;
  const int stride = gridDim.x * blockDim.x * 8;
  for (; i < n; i += stride) {
    float4 a = *(const float4*)&in[i];
    float4 b = *(const float4*)&in[i + 4];
    u16x8 t;
    t[0]=f2bf(a.x); t[1]=f2bf(a.y); t[2]=f2bf(a.z); t[3]=f2bf(a.w);
    t[4]=f2bf(b.x); t[5]=f2bf(b.y); t[6]=f2bf(b.z); t[7]=f2bf(b.w);
    *(u16x8*)&out[i] = t;
  }
}

// ---------------- fp32 [R][C] -> bf16 [C][R] transpose ----------------
__global__ void transpose_to_bf16(const float* __restrict__ in,
                                  unsigned short* __restrict__ out,
                                  int R, int Cc) {
  __shared__ float tile[32][33];
  const int c0 = blockIdx.x * 32, r0 = blockIdx.y * 32;
  const int tx = threadIdx.x & 31, ty = threadIdx.x >> 5;  // 32x8
#pragma unroll
  for (int i = 0; i < 32; i += 8)
    tile[ty + i][tx] = in[(size_t)(r0 + ty + i) * Cc + c0 + tx];
  __syncthreads();
#pragma unroll
  for (int i = 0; i < 32; i += 8)
    out[(size_t)(c0 + ty + i) * R + r0 + tx] = f2bf(tile[tx][ty + i]);
}

// ---------------- 128x128 bf16 MFMA GEMM (A [M][K], Bt [N][K]) ----------------
// MODE 0: epilogue scatters to q/k/v [B*H][T][D] bf16 (q scaled by 1/8)
// MODE 1: epilogue writes fp32 [M][N] + bias
template<int MODE>
__global__ void gemm128(const unsigned short* __restrict__ A,
                        const unsigned short* __restrict__ Bt,
                        const float* __restrict__ bias,
                        void* __restrict__ outp,
                        int M, int N, int K)
{
  __shared__ unsigned short Alds[128 * 32];
  __shared__ unsigned short Blds[128 * 32];
  const int tid = threadIdx.x;
  const int lane = tid & 63;
  const int wid  = tid >> 6;
  const int wm = wid >> 1, wn = wid & 1;
  // XCD chunked swizzle over the linearized grid
  const int nwg = (int)(gridDim.x * gridDim.y);
  const int swz = xcd_swz((int)(blockIdx.y * gridDim.x + blockIdx.x), nwg);
  const int m0 = (swz / (int)gridDim.x) * 128;
  const int n0 = (swz % (int)gridDim.x) * 128;
  const int l15 = lane & 15, l4 = lane >> 4;

  f32x4 acc[4][4];
#pragma unroll
  for (int i = 0; i < 4; i++)
#pragma unroll
    for (int j = 0; j < 4; j++) acc[i][j] = (f32x4){0.f, 0.f, 0.f, 0.f};

  for (int k0 = 0; k0 < K; k0 += 32) {
    __syncthreads();
#pragma unroll
    for (int c = 0; c < 2; ++c) {
      const int chunk = wid * 2 + c;                 // 8 chunks of 1024B
      const int linear = chunk * 1024 + lane * 16;   // byte offset in 128x32 bf16 tile
      const int row  = linear >> 6;                  // 64B per row
      const int colb = linear & 63;
      glds16((const char*)A  + ((size_t)(m0 + row) * K + k0) * 2 + colb,
             (char*)Alds + chunk * 1024);
      glds16((const char*)Bt + ((size_t)(n0 + row) * K + k0) * 2 + colb,
             (char*)Blds + chunk * 1024);
    }
    __syncthreads();
    bf16x8 af[4], bfr[4];
#pragma unroll
    for (int i = 0; i < 4; i++)
      af[i]  = *(const bf16x8*)&Alds[(wm * 64 + i * 16 + l15) * 32 + l4 * 8];
#pragma unroll
    for (int j = 0; j < 4; j++)
      bfr[j] = *(const bf16x8*)&Blds[(wn * 64 + j * 16 + l15) * 32 + l4 * 8];
#pragma unroll
    for (int i = 0; i < 4; i++)
#pragma unroll
      for (int j = 0; j < 4; j++)
        acc[i][j] = __builtin_amdgcn_mfma_f32_16x16x32_bf16(af[i], bfr[j], acc[i][j], 0, 0, 0);
  }

#pragma unroll
  for (int i = 0; i < 4; i++) {
#pragma unroll
    for (int j = 0; j < 4; j++) {
      const int n = n0 + wn * 64 + j * 16 + l15;
      const float bn = bias[n];
#pragma unroll
      for (int r = 0; r < 4; r++) {
        const int m = m0 + wm * 64 + i * 16 + l4 * 4 + r;
        float v = acc[i][j][r] + bn;
        if (MODE == 0) {
          unsigned short* qb = (unsigned short*)outp;
          const int which = n >> 10;           // 0:q 1:k 2:v
          const int cc = n & 1023;
          const int h = cc >> 6, d = cc & 63;
          const int b = m >> 11, t = m & 2047;
          const size_t off = (((size_t)(b * HH + h)) * TT + t) * DD + d;
          if (which == 0)      qb[off] = f2bf(v * 0.125f);           // fold 1/sqrt(D)
          else if (which == 1) qb[(size_t)MM * CC + off] = f2bf(v);
          else                 qb[(size_t)2 * MM * CC + off] = f2bf(v);
        } else {
          float* O = (float*)outp;
          O[(size_t)m * N + n] = v;
        }
      }
    }
  }
}

// ---------------- causal flash attention (bf16 MFMA, fp32 softmax state) ----------------
// grid: T/64 * B*H linearized; block: 256 (4 waves x 16 q-rows). KV tiles of 64.
__global__ void attn_fwd(const unsigned short* __restrict__ qbuf,
                         const unsigned short* __restrict__ kbuf,
                         const unsigned short* __restrict__ vbuf,
                         unsigned short* __restrict__ ao)
{
  __shared__ unsigned short Klds[64 * 64];      // [kv][d], swz ^((kv&7)<<3)
  __shared__ unsigned short Vt[64 * 64];        // [d][kv], swz ^((d&7)<<3)
  __shared__ unsigned short Plds[4 * 16 * 64];  // per-wave P [q][kv], swz ^((q&7)<<3)
  const int tid = threadIdx.x, lane = tid & 63, w = tid >> 6;
  const int l15 = lane & 15, l4 = lane >> 4;
  const int NQT = TT / 64;                      // 32 q-tiles
  const int nwg = NQT * BB * HH;
  const int swz = xcd_swz((int)blockIdx.x, nwg);
  const int bh = swz / NQT;                     // chunked: each XCD owns whole bh's
  const int qtile = NQT - 1 - (swz % NQT);      // long (late-diagonal) blocks first
  const int q0 = qtile * 64;
  const unsigned short* Qb = qbuf + (size_t)bh * TT * DD;
  const unsigned short* Kb = kbuf + (size_t)bh * TT * DD;
  const unsigned short* Vb = vbuf + (size_t)bh * TT * DD;

  // Q fragments, held in registers for the whole block (A-operand layout)
  bf16x8 qf[2];
#pragma unroll
  for (int ks = 0; ks < 2; ks++)
    qf[ks] = *(const bf16x8*)&Qb[(size_t)(q0 + w * 16 + l15) * DD + ks * 32 + l4 * 8];

  f32x4 o[4];
#pragma unroll
  for (int df = 0; df < 4; df++) o[df] = (f32x4){0.f, 0.f, 0.f, 0.f};
  float mrow[4] = {-__builtin_huge_valf(), -__builtin_huge_valf(),
                   -__builtin_huge_valf(), -__builtin_huge_valf()};
  float lrow[4] = {0.f, 0.f, 0.f, 0.f};

  const int qwmin = q0 + w * 16;
  const int nk = q0 + 64;
  for (int kv0 = 0; kv0 < nk; kv0 += 64) {
    __syncthreads();
    {
      // stage K [64][64] swizzled + V transposed [d][kv]; 2 rows per thread
      const int kvr0 = tid >> 3;                // 0..31
      const int c8   = (tid & 7) * 8;           // 0..56
#pragma unroll
      for (int half = 0; half < 2; half++) {
        const int kvr = kvr0 + half * 32;
        bf16x8 tk = *(const bf16x8*)&Kb[(size_t)(kv0 + kvr) * DD + c8];
        *(bf16x8*)&Klds[(kvr * 64 + c8) ^ ((kvr & 7) << 3)] = tk;
        union { bf16x8 v; unsigned short u[8]; } tv;
        tv.v = *(const bf16x8*)&Vb[(size_t)(kv0 + kvr) * DD + c8];
#pragma unroll
        for (int jj = 0; jj < 8; jj++) {
          const int d = c8 + jj;
          Vt[(d * 64 + kvr) ^ ((d & 7) << 3)] = tv.u[jj];
        }
      }
    }
    __syncthreads();

    // S = Q K^T : 4 col-fragments x (D=64 -> 2 MFMAs each)
    f32x4 s[4];
#pragma unroll
    for (int fc = 0; fc < 4; fc++) {
      s[fc] = (f32x4){0.f, 0.f, 0.f, 0.f};
      const int kr = fc * 16 + l15;
#pragma unroll
      for (int ks = 0; ks < 2; ks++) {
        bf16x8 kf = *(const bf16x8*)&Klds[(kr * 64 + ks * 32 + l4 * 8) ^ ((kr & 7) << 3)];
        s[fc] = __builtin_amdgcn_mfma_f32_16x16x32_bf16(qf[ks], kf, s[fc], 0, 0, 0);
      }
    }
    // causal mask (only the diagonal tile straddles)
    if (kv0 + 63 > qwmin) {
#pragma unroll
      for (int fc = 0; fc < 4; fc++)
#pragma unroll
        for (int r = 0; r < 4; r++) {
          const int kv = kv0 + fc * 16 + l15;
          const int q  = qwmin + l4 * 4 + r;
          if (kv > q) s[fc][r] = -__builtin_huge_valf();
        }
    }
    // online softmax, wave-parallel (16-lane row groups own 4 rows each)
    const int base = w * 1024;
#pragma unroll
    for (int r = 0; r < 4; r++) {
      float tm = fmaxf(fmaxf(s[0][r], s[1][r]), fmaxf(s[2][r], s[3][r]));
      tm = fmaxf(tm, __shfl_xor(tm, 1, 16));
      tm = fmaxf(tm, __shfl_xor(tm, 2, 16));
      tm = fmaxf(tm, __shfl_xor(tm, 4, 16));
      tm = fmaxf(tm, __shfl_xor(tm, 8, 16));
      const float mn = fmaxf(mrow[r], tm);
      const float sc = __expf(mrow[r] - mn);   // first tile: exp(-inf)=0, safe
      float p[4];
#pragma unroll
      for (int fc = 0; fc < 4; fc++) p[fc] = __expf(s[fc][r] - mn);
      float ps = (p[0] + p[1]) + (p[2] + p[3]);
      ps += __shfl_xor(ps, 1, 16);
      ps += __shfl_xor(ps, 2, 16);
      ps += __shfl_xor(ps, 4, 16);
      ps += __shfl_xor(ps, 8, 16);
      lrow[r] = lrow[r] * sc + ps;
      mrow[r] = mn;
#pragma unroll
      for (int df = 0; df < 4; df++) o[df][r] *= sc;
      const int ro = l4 * 4 + r;               // C-layout row
#pragma unroll
      for (int fc = 0; fc < 4; fc++)
        Plds[base + ((ro * 64 + fc * 16 + l15) ^ ((ro & 7) << 3))] = f2bf(p[fc]);
    }
    // PV: P (A-operand via LDS re-layout) x V, K-dim = 64 -> 2 MFMAs per d-frag
    bf16x8 pa[2];
#pragma unroll
    for (int ks = 0; ks < 2; ks++)
      pa[ks] = *(const bf16x8*)&Plds[base + ((l15 * 64 + ks * 32 + l4 * 8) ^ ((l15 & 7) << 3))];
#pragma unroll
    for (int df = 0; df < 4; df++) {
      const int d = df * 16 + l15;
#pragma unroll
      for (int ks = 0; ks < 2; ks++) {
        bf16x8 vf = *(const bf16x8*)&Vt[(d * 64 + ks * 32 + l4 * 8) ^ ((d & 7) << 3)];
        o[df] = __builtin_amdgcn_mfma_f32_16x16x32_bf16(pa[ks], vf, o[df], 0, 0, 0);
      }
    }
  }

  // epilogue: normalize, write [B,T,H*D] bf16 for the out-proj GEMM
  const int b = bh >> 4, h = bh & 15;
#pragma unroll
  for (int r = 0; r < 4; r++) {
    const float inv = 1.0f / lrow[r];
    const int q = qwmin + l4 * 4 + r;
#pragma unroll
    for (int df = 0; df < 4; df++) {
      const int d = df * 16 + l15;
      ao[((size_t)(b * TT + q)) * CC + h * DD + d] = f2bf(o[df][r] * inv);
    }
  }
}

// ---------------- launch ----------------
extern "C" void kernel_launch(void* const* d_in, const int* in_sizes, int n_in,
                              void* d_out, int out_size, void* d_ws, size_t ws_size,
                              hipStream_t stream) {
  const float* x    = (const float*)d_in[0];
  const float* Wqkv = (const float*)d_in[1];
  const float* bqkv = (const float*)d_in[2];
  const float* Wout = (const float*)d_in[3];
  const float* bout = (const float*)d_in[4];
  float* out = (float*)d_out;
  char* ws = (char*)d_ws;

  // workspace layout (72 MB total)
  unsigned short* xb    = (unsigned short*)ws;                       // 16 MB, M*C bf16
  unsigned short* wqkvt = (unsigned short*)(ws + 16777216);          // 6 MB, [3C][C]
  unsigned short* woutt = (unsigned short*)(ws + 23068672);          // 2 MB, [C][C]
  unsigned short* qkv   = (unsigned short*)(ws + 25165824);          // 48 MB, q|k|v [B*H][T][D]
  unsigned short* ao    = xb;                                        // reuse xb after QKV GEMM

  f32_to_bf16_kn<<<2048, 256, 0, stream>>>(x, xb, MM * CC);
  transpose_to_bf16<<<dim3(3 * CC / 32, CC / 32), 256, 0, stream>>>(Wqkv, wqkvt, CC, 3 * CC);
  transpose_to_bf16<<<dim3(CC / 32, CC / 32), 256, 0, stream>>>(Wout, woutt, CC, CC);

  gemm128<0><<<dim3(3 * CC / 128, MM / 128), 256, 0, stream>>>(
      xb, wqkvt, bqkv, (void*)qkv, MM, 3 * CC, CC);

  attn_fwd<<<(TT / 64) * BB * HH, 256, 0, stream>>>(
      qkv, qkv + (size_t)MM * CC, qkv + (size_t)2 * MM * CC, ao);

  gemm128<1><<<dim3(CC / 128, MM / 128), 256, 0, stream>>>(
      ao, woutt, bout, (void*)out, MM, CC, CC);
}

// Round 4
// 338.120 us; speedup vs baseline: 1.1703x; 1.1703x over previous
//
#include <hip/hip_runtime.h>
#include <stdint.h>

// Problem constants (fixed by the reference)
#define BB 4
#define TT 2048
#define CC 1024
#define HH 16
#define DD 64
#define MM (BB*TT)   // 8192 rows

typedef __bf16 bf16x8 __attribute__((ext_vector_type(8)));
typedef float  f32x4  __attribute__((ext_vector_type(4)));

__device__ __forceinline__ unsigned short f2bf(float f) {
  __bf16 h = (__bf16)f;
  union { __bf16 h; unsigned short u; } c; c.h = h;
  return c.u;
}

// async global->LDS, 16B per lane; LDS dest is wave-uniform base + lane*16
__device__ __forceinline__ void glds16(const void* g, void* l) {
  __builtin_amdgcn_global_load_lds((const __attribute__((address_space(1))) void*)g,
                                   (__attribute__((address_space(3))) void*)l,
                                   16, 0, 0);
}

// XCD-aware chunked swizzle (bijective; requires nwg % 8 == 0)
__device__ __forceinline__ int xcd_swz(int bid, int nwg) {
  if (nwg & 7) return bid;
  return (bid & 7) * (nwg >> 3) + (bid >> 3);
}

// ---------------- fp32 -> bf16 bulk convert ----------------
typedef unsigned short u16x8 __attribute__((ext_vector_type(8)));
__global__ void f32_to_bf16_kn(const float* __restrict__ in,
                               unsigned short* __restrict__ out, int n) {
  int i = (blockIdx.x * blockDim.x + threadIdx.x) * 8;
  const int stride = gridDim.x * blockDim.x * 8;
  for (; i < n; i += stride) {
    float4 a = *(const float4*)&in[i];
    float4 b = *(const float4*)&in[i + 4];
    u16x8 t;
    t[0]=f2bf(a.x); t[1]=f2bf(a.y); t[2]=f2bf(a.z); t[3]=f2bf(a.w);
    t[4]=f2bf(b.x); t[5]=f2bf(b.y); t[6]=f2bf(b.z); t[7]=f2bf(b.w);
    *(u16x8*)&out[i] = t;
  }
}

// ---------------- fp32 [R][C] -> bf16 [C][R] transpose ----------------
__global__ void transpose_to_bf16(const float* __restrict__ in,
                                  unsigned short* __restrict__ out,
                                  int R, int Cc) {
  __shared__ float tile[32][33];
  const int c0 = blockIdx.x * 32, r0 = blockIdx.y * 32;
  const int tx = threadIdx.x & 31, ty = threadIdx.x >> 5;  // 32x8
#pragma unroll
  for (int i = 0; i < 32; i += 8)
    tile[ty + i][tx] = in[(size_t)(r0 + ty + i) * Cc + c0 + tx];
  __syncthreads();
#pragma unroll
  for (int i = 0; i < 32; i += 8)
    out[(size_t)(c0 + ty + i) * R + r0 + tx] = f2bf(tile[tx][ty + i]);
}

// ---------------- 128x128 bf16 MFMA GEMM (A [M][K], Bt [N][K]) ----------------
// MODE 0: epilogue scatters q [bh][T][D] (scaled 1/8), k [bh][T][D], v TRANSPOSED [bh][D][T]
// MODE 1: epilogue writes fp32 [M][N] + bias
template<int MODE>
__global__ void gemm128(const unsigned short* __restrict__ A,
                        const unsigned short* __restrict__ Bt,
                        const float* __restrict__ bias,
                        void* __restrict__ outp,
                        int M, int N, int K)
{
  __shared__ unsigned short Alds[128 * 32];
  __shared__ unsigned short Blds[128 * 32];
  const int tid = threadIdx.x;
  const int lane = tid & 63;
  const int wid  = tid >> 6;
  const int wm = wid >> 1, wn = wid & 1;
  const int nwg = (int)(gridDim.x * gridDim.y);
  const int swz = xcd_swz((int)(blockIdx.y * gridDim.x + blockIdx.x), nwg);
  const int m0 = (swz / (int)gridDim.x) * 128;
  const int n0 = (swz % (int)gridDim.x) * 128;
  const int l15 = lane & 15, l4 = lane >> 4;

  f32x4 acc[4][4];
#pragma unroll
  for (int i = 0; i < 4; i++)
#pragma unroll
    for (int j = 0; j < 4; j++) acc[i][j] = (f32x4){0.f, 0.f, 0.f, 0.f};

  for (int k0 = 0; k0 < K; k0 += 32) {
    __syncthreads();
#pragma unroll
    for (int c = 0; c < 2; ++c) {
      const int chunk = wid * 2 + c;                 // 8 chunks of 1024B
      const int linear = chunk * 1024 + lane * 16;   // byte offset in 128x32 bf16 tile
      const int row  = linear >> 6;                  // 64B per row
      const int colb = linear & 63;
      glds16((const char*)A  + ((size_t)(m0 + row) * K + k0) * 2 + colb,
             (char*)Alds + chunk * 1024);
      glds16((const char*)Bt + ((size_t)(n0 + row) * K + k0) * 2 + colb,
             (char*)Blds + chunk * 1024);
    }
    __syncthreads();
    bf16x8 af[4], bfr[4];
#pragma unroll
    for (int i = 0; i < 4; i++)
      af[i]  = *(const bf16x8*)&Alds[(wm * 64 + i * 16 + l15) * 32 + l4 * 8];
#pragma unroll
    for (int j = 0; j < 4; j++)
      bfr[j] = *(const bf16x8*)&Blds[(wn * 64 + j * 16 + l15) * 32 + l4 * 8];
#pragma unroll
    for (int i = 0; i < 4; i++)
#pragma unroll
      for (int j = 0; j < 4; j++)
        acc[i][j] = __builtin_amdgcn_mfma_f32_16x16x32_bf16(af[i], bfr[j], acc[i][j], 0, 0, 0);
  }

#pragma unroll
  for (int i = 0; i < 4; i++) {
#pragma unroll
    for (int j = 0; j < 4; j++) {
      const int n = n0 + wn * 64 + j * 16 + l15;
      const float bn = bias[n];
#pragma unroll
      for (int r = 0; r < 4; r++) {
        const int m = m0 + wm * 64 + i * 16 + l4 * 4 + r;
        float v = acc[i][j][r] + bn;
        if (MODE == 0) {
          unsigned short* qb = (unsigned short*)outp;
          const int which = n >> 10;           // 0:q 1:k 2:v
          const int cc = n & 1023;
          const int h = cc >> 6, d = cc & 63;
          const int b = m >> 11, t = m & 2047;
          if (which == 0) {
            const size_t off = (((size_t)(b * HH + h)) * TT + t) * DD + d;
            qb[off] = f2bf(v * 0.125f);                        // fold 1/sqrt(D)
          } else if (which == 1) {
            const size_t off = (((size_t)(b * HH + h)) * TT + t) * DD + d;
            qb[(size_t)MM * CC + off] = f2bf(v);
          } else {
            // V stored TRANSPOSED: [bh][D][T]
            const size_t offv = (((size_t)(b * HH + h)) * DD + d) * TT + t;
            qb[(size_t)2 * MM * CC + offv] = f2bf(v);
          }
        } else {
          float* O = (float*)outp;
          O[(size_t)m * N + n] = v;
        }
      }
    }
  }
}

// ---------------- causal flash attention ----------------
// grid: T/64 * B*H linearized; block: 256 (4 waves x 16 q-rows). KV tiles of 64.
// K [bh][T][D]; V^T [bh][D][T]. Both staged async via global_load_lds with
// pre-swizzled SOURCE (swizzle ^((row&7)<<3) on elements = 16B-chunk permute per row),
// double-buffered, one barrier per tile.
__global__ void attn_fwd(const unsigned short* __restrict__ qbuf,
                         const unsigned short* __restrict__ kbuf,
                         const unsigned short* __restrict__ vtbuf,
                         unsigned short* __restrict__ ao)
{
  __shared__ unsigned short Klds[2][64 * 64];   // [kv][d], swz ^((kv&7)<<3)
  __shared__ unsigned short Vt[2][64 * 64];     // [d][kv], swz ^((d&7)<<3)
  __shared__ unsigned short Plds[4 * 16 * 64];  // per-wave P [q][kv], swz ^((q&7)<<3)
  const int tid = threadIdx.x, lane = tid & 63, w = tid >> 6;
  const int l15 = lane & 15, l4 = lane >> 4;
  const int NQT = TT / 64;                      // 32 q-tiles
  const int nwg = NQT * BB * HH;
  const int swz = xcd_swz((int)blockIdx.x, nwg);
  const int bh = swz / NQT;                     // chunked: each XCD owns whole bh's
  const int qtile = NQT - 1 - (swz % NQT);      // long (late-diagonal) blocks first
  const int q0 = qtile * 64;
  const unsigned short* Qb  = qbuf  + (size_t)bh * TT * DD;
  const unsigned short* Kb  = kbuf  + (size_t)bh * TT * DD;
  const unsigned short* VTb = vtbuf + (size_t)bh * DD * TT;

  // staging geometry: per wave 2 glds16 per tile per tensor; lane l covers
  // LDS linear chunk (w*2+j)*64+l (16B units): row=(w*2+j)*8 + l/8,
  // source chunk-in-row = (l&7) ^ (l>>3)  (involution => LDS holds swizzled layout)
  const int srow = lane >> 3;
  const int scol = ((lane & 7) ^ srow) * 8;     // element offset within row

  // Q fragments, held in registers for the whole block (A-operand layout)
  bf16x8 qf[2];
#pragma unroll
  for (int ks = 0; ks < 2; ks++)
    qf[ks] = *(const bf16x8*)&Qb[(size_t)(q0 + w * 16 + l15) * DD + ks * 32 + l4 * 8];

  f32x4 o[4];
#pragma unroll
  for (int df = 0; df < 4; df++) o[df] = (f32x4){0.f, 0.f, 0.f, 0.f};
  float mrow[4] = {-__builtin_huge_valf(), -__builtin_huge_valf(),
                   -__builtin_huge_valf(), -__builtin_huge_valf()};
  float lrow[4] = {0.f, 0.f, 0.f, 0.f};

  const int qwmin = q0 + w * 16;
  const int nt = qtile + 1;

  // prologue: issue tile 0 into buffer 0
#pragma unroll
  for (int j = 0; j < 2; j++) {
    const int g = w * 2 + j;
    const int row = g * 8 + srow;
    glds16(Kb + (size_t)row * DD + scol,       (char*)&Klds[0][0] + g * 1024);
    glds16(VTb + (size_t)row * TT + scol,      (char*)&Vt[0][0]   + g * 1024);
  }

  for (int t = 0; t < nt; t++) {
    // implicit vmcnt(0)+lgkmcnt(0) drain: tile t's loads (issued one full
    // compute-phase ago) land; also gates buffer reuse across waves.
    __syncthreads();
    if (t + 1 < nt) {
      const int kv1 = (t + 1) * 64;
      const int nb = (t + 1) & 1;
#pragma unroll
      for (int j = 0; j < 2; j++) {
        const int g = w * 2 + j;
        const int row = g * 8 + srow;
        glds16(Kb + (size_t)(kv1 + row) * DD + scol, (char*)&Klds[nb][0] + g * 1024);
        glds16(VTb + (size_t)row * TT + kv1 + scol,  (char*)&Vt[nb][0]   + g * 1024);
      }
    }
    const int cb = t & 1;
    const int kv0 = t * 64;

    // S = Q K^T : 4 col-fragments x (D=64 -> 2 MFMAs each)
    f32x4 s[4];
#pragma unroll
    for (int fc = 0; fc < 4; fc++) {
      s[fc] = (f32x4){0.f, 0.f, 0.f, 0.f};
      const int kr = fc * 16 + l15;
#pragma unroll
      for (int ks = 0; ks < 2; ks++) {
        bf16x8 kf = *(const bf16x8*)&Klds[cb][(kr * 64 + ks * 32 + l4 * 8) ^ ((kr & 7) << 3)];
        s[fc] = __builtin_amdgcn_mfma_f32_16x16x32_bf16(qf[ks], kf, s[fc], 0, 0, 0);
      }
    }
    // causal mask (only the diagonal tile straddles)
    if (kv0 + 63 > qwmin) {
#pragma unroll
      for (int fc = 0; fc < 4; fc++)
#pragma unroll
        for (int r = 0; r < 4; r++) {
          const int kv = kv0 + fc * 16 + l15;
          const int q  = qwmin + l4 * 4 + r;
          if (kv > q) s[fc][r] = -__builtin_huge_valf();
        }
    }
    // online softmax, wave-parallel (16-lane row groups own 4 rows each)
    const int base = w * 1024;
#pragma unroll
    for (int r = 0; r < 4; r++) {
      float tm = fmaxf(fmaxf(s[0][r], s[1][r]), fmaxf(s[2][r], s[3][r]));
      tm = fmaxf(tm, __shfl_xor(tm, 1, 16));
      tm = fmaxf(tm, __shfl_xor(tm, 2, 16));
      tm = fmaxf(tm, __shfl_xor(tm, 4, 16));
      tm = fmaxf(tm, __shfl_xor(tm, 8, 16));
      const float mn = fmaxf(mrow[r], tm);
      const float sc = __expf(mrow[r] - mn);   // first tile: exp(-inf)=0, safe
      float p[4];
#pragma unroll
      for (int fc = 0; fc < 4; fc++) p[fc] = __expf(s[fc][r] - mn);
      float ps = (p[0] + p[1]) + (p[2] + p[3]);
      ps += __shfl_xor(ps, 1, 16);
      ps += __shfl_xor(ps, 2, 16);
      ps += __shfl_xor(ps, 4, 16);
      ps += __shfl_xor(ps, 8, 16);
      lrow[r] = lrow[r] * sc + ps;
      mrow[r] = mn;
#pragma unroll
      for (int df = 0; df < 4; df++) o[df][r] *= sc;
      const int ro = l4 * 4 + r;               // C-layout row
#pragma unroll
      for (int fc = 0; fc < 4; fc++)
        Plds[base + ((ro * 64 + fc * 16 + l15) ^ ((ro & 7) << 3))] = f2bf(p[fc]);
    }
    // PV: P (A-operand via LDS re-layout) x V^T, K-dim = 64 -> 2 MFMAs per d-frag
    bf16x8 pa[2];
#pragma unroll
    for (int ks = 0; ks < 2; ks++)
      pa[ks] = *(const bf16x8*)&Plds[base + ((l15 * 64 + ks * 32 + l4 * 8) ^ ((l15 & 7) << 3))];
#pragma unroll
    for (int df = 0; df < 4; df++) {
      const int d = df * 16 + l15;
#pragma unroll
      for (int ks = 0; ks < 2; ks++) {
        bf16x8 vf = *(const bf16x8*)&Vt[cb][(d * 64 + ks * 32 + l4 * 8) ^ ((d & 7) << 3)];
        o[df] = __builtin_amdgcn_mfma_f32_16x16x32_bf16(pa[ks], vf, o[df], 0, 0, 0);
      }
    }
  }

  // epilogue: normalize, write [B,T,H*D] bf16 for the out-proj GEMM
  const int b = bh >> 4, h = bh & 15;
#pragma unroll
  for (int r = 0; r < 4; r++) {
    const float inv = 1.0f / lrow[r];
    const int q = qwmin + l4 * 4 + r;
#pragma unroll
    for (int df = 0; df < 4; df++) {
      const int d = df * 16 + l15;
      ao[((size_t)(b * TT + q)) * CC + h * DD + d] = f2bf(o[df][r] * inv);
    }
  }
}

// ---------------- launch ----------------
extern "C" void kernel_launch(void* const* d_in, const int* in_sizes, int n_in,
                              void* d_out, int out_size, void* d_ws, size_t ws_size,
                              hipStream_t stream) {
  const float* x    = (const float*)d_in[0];
  const float* Wqkv = (const float*)d_in[1];
  const float* bqkv = (const float*)d_in[2];
  const float* Wout = (const float*)d_in[3];
  const float* bout = (const float*)d_in[4];
  float* out = (float*)d_out;
  char* ws = (char*)d_ws;

  // workspace layout (72 MB total)
  unsigned short* xb    = (unsigned short*)ws;                       // 16 MB, M*C bf16
  unsigned short* wqkvt = (unsigned short*)(ws + 16777216);          // 6 MB, [3C][C]
  unsigned short* woutt = (unsigned short*)(ws + 23068672);          // 2 MB, [C][C]
  unsigned short* qkv   = (unsigned short*)(ws + 25165824);          // 48 MB, q|k|vT
  unsigned short* ao    = xb;                                        // reuse xb after QKV GEMM

  f32_to_bf16_kn<<<2048, 256, 0, stream>>>(x, xb, MM * CC);
  transpose_to_bf16<<<dim3(3 * CC / 32, CC / 32), 256, 0, stream>>>(Wqkv, wqkvt, CC, 3 * CC);
  transpose_to_bf16<<<dim3(CC / 32, CC / 32), 256, 0, stream>>>(Wout, woutt, CC, CC);

  gemm128<0><<<dim3(3 * CC / 128, MM / 128), 256, 0, stream>>>(
      xb, wqkvt, bqkv, (void*)qkv, MM, 3 * CC, CC);

  attn_fwd<<<(TT / 64) * BB * HH, 256, 0, stream>>>(
      qkv, qkv + (size_t)MM * CC, qkv + (size_t)2 * MM * CC, ao);

  gemm128<1><<<dim3(CC / 128, MM / 128), 256, 0, stream>>>(
      ao, woutt, bout, (void*)out, MM, CC, CC);
}

// Round 8
// 297.610 us; speedup vs baseline: 1.3296x; 1.1361x over previous
//
#include <hip/hip_runtime.h>
#include <stdint.h>

// Problem constants (fixed by the reference)
#define BB 4
#define TT 2048
#define CC 1024
#define HH 16
#define DD 64
#define MM (BB*TT)   // 8192 rows

typedef __bf16 bf16x8 __attribute__((ext_vector_type(8)));
typedef float  f32x4  __attribute__((ext_vector_type(4)));

__device__ __forceinline__ unsigned short f2bf(float f) {
  __bf16 h = (__bf16)f;
  union { __bf16 h; unsigned short u; } c; c.h = h;
  return c.u;
}

// async global->LDS, 16B per lane; LDS dest is wave-uniform base + lane*16
__device__ __forceinline__ void glds16(const void* g, void* l) {
  __builtin_amdgcn_global_load_lds((const __attribute__((address_space(1))) void*)g,
                                   (__attribute__((address_space(3))) void*)l,
                                   16, 0, 0);
}

// gfx950 half-wave / 16-row register swaps (VALU, not LDS pipe)
__device__ __forceinline__ void perm32swap(uint32_t& a, uint32_t& b) {
  asm volatile("v_permlane32_swap_b32 %0, %1" : "+v"(a), "+v"(b));
}
__device__ __forceinline__ void perm16swap(uint32_t& a, uint32_t& b) {
  asm volatile("v_permlane16_swap_b32 %0, %1" : "+v"(a), "+v"(b));
}

// XCD-aware chunked swizzle (bijective; requires nwg % 8 == 0)
__device__ __forceinline__ int xcd_swz(int bid, int nwg) {
  if (nwg & 7) return bid;
  return (bid & 7) * (nwg >> 3) + (bid >> 3);
}

// ---------------- fp32 -> bf16 bulk convert ----------------
typedef unsigned short u16x8 __attribute__((ext_vector_type(8)));
__global__ void f32_to_bf16_kn(const float* __restrict__ in,
                               unsigned short* __restrict__ out, int n) {
  int i = (blockIdx.x * blockDim.x + threadIdx.x) * 8;
  const int stride = gridDim.x * blockDim.x * 8;
  for (; i < n; i += stride) {
    float4 a = *(const float4*)&in[i];
    float4 b = *(const float4*)&in[i + 4];
    u16x8 t;
    t[0]=f2bf(a.x); t[1]=f2bf(a.y); t[2]=f2bf(a.z); t[3]=f2bf(a.w);
    t[4]=f2bf(b.x); t[5]=f2bf(b.y); t[6]=f2bf(b.z); t[7]=f2bf(b.w);
    *(u16x8*)&out[i] = t;
  }
}

// ---------------- fp32 [R][C] -> bf16 [C][R] transpose ----------------
__global__ void transpose_to_bf16(const float* __restrict__ in,
                                  unsigned short* __restrict__ out,
                                  int R, int Cc) {
  __shared__ float tile[32][33];
  const int c0 = blockIdx.x * 32, r0 = blockIdx.y * 32;
  const int tx = threadIdx.x & 31, ty = threadIdx.x >> 5;  // 32x8
#pragma unroll
  for (int i = 0; i < 32; i += 8)
    tile[ty + i][tx] = in[(size_t)(r0 + ty + i) * Cc + c0 + tx];
  __syncthreads();
#pragma unroll
  for (int i = 0; i < 32; i += 8)
    out[(size_t)(c0 + ty + i) * R + r0 + tx] = f2bf(tile[tx][ty + i]);
}

// ---------------- 128x128 bf16 MFMA GEMM (A [M][K], Bt [N][K]) ----------------
// MODE 0: epilogue scatters q [bh][T][D] (scaled 1/8), k [bh][T][D], v TRANSPOSED [bh][D][T]
// MODE 1: epilogue writes fp32 [M][N] + bias
template<int MODE>
__global__ void gemm128(const unsigned short* __restrict__ A,
                        const unsigned short* __restrict__ Bt,
                        const float* __restrict__ bias,
                        void* __restrict__ outp,
                        int M, int N, int K)
{
  __shared__ unsigned short Alds[128 * 32];
  __shared__ unsigned short Blds[128 * 32];
  const int tid = threadIdx.x;
  const int lane = tid & 63;
  const int wid  = tid >> 6;
  const int wm = wid >> 1, wn = wid & 1;
  const int nwg = (int)(gridDim.x * gridDim.y);
  const int swz = xcd_swz((int)(blockIdx.y * gridDim.x + blockIdx.x), nwg);
  const int m0 = (swz / (int)gridDim.x) * 128;
  const int n0 = (swz % (int)gridDim.x) * 128;
  const int l15 = lane & 15, l4 = lane >> 4;

  f32x4 acc[4][4];
#pragma unroll
  for (int i = 0; i < 4; i++)
#pragma unroll
    for (int j = 0; j < 4; j++) acc[i][j] = (f32x4){0.f, 0.f, 0.f, 0.f};

  for (int k0 = 0; k0 < K; k0 += 32) {
    __syncthreads();
#pragma unroll
    for (int c = 0; c < 2; ++c) {
      const int chunk = wid * 2 + c;                 // 8 chunks of 1024B
      const int linear = chunk * 1024 + lane * 16;   // byte offset in 128x32 bf16 tile
      const int row  = linear >> 6;                  // 64B per row
      const int colb = linear & 63;
      glds16((const char*)A  + ((size_t)(m0 + row) * K + k0) * 2 + colb,
             (char*)Alds + chunk * 1024);
      glds16((const char*)Bt + ((size_t)(n0 + row) * K + k0) * 2 + colb,
             (char*)Blds + chunk * 1024);
    }
    __syncthreads();
    bf16x8 af[4], bfr[4];
#pragma unroll
    for (int i = 0; i < 4; i++)
      af[i]  = *(const bf16x8*)&Alds[(wm * 64 + i * 16 + l15) * 32 + l4 * 8];
#pragma unroll
    for (int j = 0; j < 4; j++)
      bfr[j] = *(const bf16x8*)&Blds[(wn * 64 + j * 16 + l15) * 32 + l4 * 8];
#pragma unroll
    for (int i = 0; i < 4; i++)
#pragma unroll
      for (int j = 0; j < 4; j++)
        acc[i][j] = __builtin_amdgcn_mfma_f32_16x16x32_bf16(af[i], bfr[j], acc[i][j], 0, 0, 0);
  }

#pragma unroll
  for (int i = 0; i < 4; i++) {
#pragma unroll
    for (int j = 0; j < 4; j++) {
      const int n = n0 + wn * 64 + j * 16 + l15;
      const float bn = bias[n];
#pragma unroll
      for (int r = 0; r < 4; r++) {
        const int m = m0 + wm * 64 + i * 16 + l4 * 4 + r;
        float v = acc[i][j][r] + bn;
        if (MODE == 0) {
          unsigned short* qb = (unsigned short*)outp;
          const int which = n >> 10;           // 0:q 1:k 2:v
          const int cc = n & 1023;
          const int h = cc >> 6, d = cc & 63;
          const int b = m >> 11, t = m & 2047;
          if (which == 0) {
            const size_t off = (((size_t)(b * HH + h)) * TT + t) * DD + d;
            qb[off] = f2bf(v * 0.125f);                        // fold 1/sqrt(D)
          } else if (which == 1) {
            const size_t off = (((size_t)(b * HH + h)) * TT + t) * DD + d;
            qb[(size_t)MM * CC + off] = f2bf(v);
          } else {
            // V stored TRANSPOSED: [bh][D][T]
            const size_t offv = (((size_t)(b * HH + h)) * DD + d) * TT + t;
            qb[(size_t)2 * MM * CC + offv] = f2bf(v);
          }
        } else {
          float* O = (float*)outp;
          O[(size_t)m * N + n] = v;
        }
      }
    }
  }
}

// ---------------- causal flash attention (swapped-operand, in-register softmax) ----
// grid: T/64 * B*H linearized; block: 256 (4 waves x 16 q-rows). KV tiles of 64.
// K [bh][T][D]; V^T [bh][D][T], staged async via global_load_lds with pre-swizzled
// source, double-buffered, one barrier per tile.
// Core: S^T = mfma(K, Q)  -> lane holds q = lane&15, kv = fc*16 + (lane>>4)*4 + r
//       softmax fully in-register (2 shuffles per reduce)
//       P^T -> operand frag via cvt-pack + permlane32/16 swaps (no LDS)
//       O^T = mfma(V^T, P^T) -> q = lane&15 matches softmax state; rescale is scalar
__global__ void attn_fwd(const unsigned short* __restrict__ qbuf,
                         const unsigned short* __restrict__ kbuf,
                         const unsigned short* __restrict__ vtbuf,
                         unsigned short* __restrict__ ao)
{
  __shared__ unsigned short Klds[2][64 * 64];   // [kv][d], swz ^((kv&7)<<3)
  __shared__ unsigned short Vt[2][64 * 64];     // [d][kv], swz ^((d&7)<<3)
  const int tid = threadIdx.x, lane = tid & 63, w = tid >> 6;
  const int l15 = lane & 15, l4 = lane >> 4;
  const int NQT = TT / 64;                      // 32 q-tiles
  const int nwg = NQT * BB * HH;
  const int swz = xcd_swz((int)blockIdx.x, nwg);
  const int bh = swz / NQT;                     // chunked: each XCD owns whole bh's
  const int qtile = NQT - 1 - (swz % NQT);      // long (late-diagonal) blocks first
  const int q0 = qtile * 64;
  const unsigned short* Qb  = qbuf  + (size_t)bh * TT * DD;
  const unsigned short* Kb  = kbuf  + (size_t)bh * TT * DD;
  const unsigned short* VTb = vtbuf + (size_t)bh * DD * TT;

  // staging geometry (unchanged from measured-good R4): per wave 2 glds16 per
  // tile per tensor; source chunk-in-row = (l&7) ^ (l>>3) pre-applies the
  // read-side XOR swizzle.
  const int srow = lane >> 3;
  const int scol = ((lane & 7) ^ srow) * 8;     // element offset within row

  // Q fragments (operand layout: l15 = q row, l4*8 = k-slot) for the whole block
  bf16x8 qf[2];
#pragma unroll
  for (int ks = 0; ks < 2; ks++)
    qf[ks] = *(const bf16x8*)&Qb[(size_t)(q0 + w * 16 + l15) * DD + ks * 32 + l4 * 8];

  // O^T accumulator: q = l15, d = df*16 + l4*4 + r
  f32x4 o[4];
#pragma unroll
  for (int df = 0; df < 4; df++) o[df] = (f32x4){0.f, 0.f, 0.f, 0.f};
  float m_st = -__builtin_huge_valf();          // per-lane: one q row
  float l_st = 0.f;

  const int qwmin = q0 + w * 16;
  const int qrow  = qwmin + l15;
  const int nt = qtile + 1;

  // prologue: issue tile 0 into buffer 0
#pragma unroll
  for (int j = 0; j < 2; j++) {
    const int g = w * 2 + j;
    const int row = g * 8 + srow;
    glds16(Kb + (size_t)row * DD + scol,       (char*)&Klds[0][0] + g * 1024);
    glds16(VTb + (size_t)row * TT + scol,      (char*)&Vt[0][0]   + g * 1024);
  }

  for (int t = 0; t < nt; t++) {
    // barrier's implicit vmcnt(0)/lgkmcnt(0) drain lands tile t and gates reuse
    __syncthreads();
    if (t + 1 < nt) {
      const int kv1 = (t + 1) * 64;
      const int nb = (t + 1) & 1;
#pragma unroll
      for (int j = 0; j < 2; j++) {
        const int g = w * 2 + j;
        const int row = g * 8 + srow;
        glds16(Kb + (size_t)(kv1 + row) * DD + scol, (char*)&Klds[nb][0] + g * 1024);
        glds16(VTb + (size_t)row * TT + kv1 + scol,  (char*)&Vt[nb][0]   + g * 1024);
      }
    }
    const int cb = t & 1;
    const int kv0 = t * 64;

    if (kv0 <= qwmin + 15) {                    // wave has >=1 unmasked row
      // S^T = K Q^T : C[kv][q]; col=l15=q, row=l4*4+r=kv (within fc*16 block)
      f32x4 s[4];
      __builtin_amdgcn_s_setprio(1);
#pragma unroll
      for (int fc = 0; fc < 4; fc++) {
        s[fc] = (f32x4){0.f, 0.f, 0.f, 0.f};
        const int kr = fc * 16 + l15;
#pragma unroll
        for (int ks = 0; ks < 2; ks++) {
          bf16x8 kf = *(const bf16x8*)&Klds[cb][(kr * 64 + ks * 32 + l4 * 8) ^ ((kr & 7) << 3)];
          s[fc] = __builtin_amdgcn_mfma_f32_16x16x32_bf16(kf, qf[ks], s[fc], 0, 0, 0);
        }
      }
      __builtin_amdgcn_s_setprio(0);
      // causal mask (only the diagonal tile straddles)
      if (kv0 + 63 > qwmin) {
#pragma unroll
        for (int fc = 0; fc < 4; fc++)
#pragma unroll
          for (int r = 0; r < 4; r++)
            if (kv0 + fc * 16 + l4 * 4 + r > qrow) s[fc][r] = -__builtin_huge_valf();
      }
      // in-register online softmax (per-lane row; 2 shuffles per reduce)
      float tm = s[0][0];
#pragma unroll
      for (int fc = 0; fc < 4; fc++)
#pragma unroll
        for (int r = 0; r < 4; r++) tm = fmaxf(tm, s[fc][r]);
      tm = fmaxf(tm, __shfl_xor(tm, 16));
      tm = fmaxf(tm, __shfl_xor(tm, 32));
      const float mn = fmaxf(m_st, tm);
      const float sc = __expf(m_st - mn);       // first tile: exp(-inf)=0, safe
      m_st = mn;
      float rs = 0.f;
      uint32_t wpk[4][2];                       // packed bf16 pairs (r0r1),(r2r3)
#pragma unroll
      for (int fc = 0; fc < 4; fc++) {
        float p0 = __expf(s[fc][0] - mn), p1 = __expf(s[fc][1] - mn);
        float p2 = __expf(s[fc][2] - mn), p3 = __expf(s[fc][3] - mn);
        rs += (p0 + p1) + (p2 + p3);
        union { unsigned short u[2]; uint32_t d; } a, b;
        a.u[0] = f2bf(p0); a.u[1] = f2bf(p1);
        b.u[0] = f2bf(p2); b.u[1] = f2bf(p3);
        wpk[fc][0] = a.d; wpk[fc][1] = b.d;
      }
      rs += __shfl_xor(rs, 16);
      rs += __shfl_xor(rs, 32);
      l_st = l_st * sc + rs;
#pragma unroll
      for (int df = 0; df < 4; df++)
#pragma unroll
        for (int r = 0; r < 4; r++) o[df][r] *= sc;
      // P^T (C-layout) -> operand frag, pure register permutation:
      // target lane(l15,l4) needs P[q=l15][kv=ks*32+l4*8+j], j=0..7.
      // quarters by l4: dw0=[A0|A2|C0|C2] dw1=[B0|B2|D0|D2] dw2=[A1|A3|C1|C3]
      // dw3=[B1|B3|D1|D3] where A=wpk[2ks][0],B=wpk[2ks][1],C=wpk[2ks+1][0],
      // D=wpk[2ks+1][1]; realized by permlane32_swap then permlane16_swap.
      bf16x8 pa[2];
#pragma unroll
      for (int ks = 0; ks < 2; ks++) {
        uint32_t Aq = wpk[2 * ks][0], Bq = wpk[2 * ks][1];
        uint32_t Cq = wpk[2 * ks + 1][0], Dq = wpk[2 * ks + 1][1];
        perm32swap(Aq, Cq); perm16swap(Aq, Cq);
        perm32swap(Bq, Dq); perm16swap(Bq, Dq);
        union { uint32_t d[4]; bf16x8 v; } pf;
        pf.d[0] = Aq; pf.d[1] = Bq; pf.d[2] = Cq; pf.d[3] = Dq;
        pa[ks] = pf.v;
      }
      // O^T += V^T x P^T : C[d][q]; col=l15=q (matches softmax state)
      __builtin_amdgcn_s_setprio(1);
#pragma unroll
      for (int df = 0; df < 4; df++) {
        const int d = df * 16 + l15;
#pragma unroll
        for (int ks = 0; ks < 2; ks++) {
          bf16x8 vf = *(const bf16x8*)&Vt[cb][(d * 64 + ks * 32 + l4 * 8) ^ ((d & 7) << 3)];
          o[df] = __builtin_amdgcn_mfma_f32_16x16x32_bf16(vf, pa[ks], o[df], 0, 0, 0);
        }
      }
      __builtin_amdgcn_s_setprio(0);
    }
  }

  // epilogue: normalize, write [B,T,H*D] bf16 for the out-proj GEMM
  const int b = bh >> 4, h = bh & 15;
  const float inv = 1.0f / l_st;
#pragma unroll
  for (int df = 0; df < 4; df++)
#pragma unroll
    for (int r = 0; r < 4; r++) {
      const int d = df * 16 + l4 * 4 + r;
      ao[((size_t)(b * TT + qrow)) * CC + h * DD + d] = f2bf(o[df][r] * inv);
    }
}

// ---------------- launch ----------------
extern "C" void kernel_launch(void* const* d_in, const int* in_sizes, int n_in,
                              void* d_out, int out_size, void* d_ws, size_t ws_size,
                              hipStream_t stream) {
  const float* x    = (const float*)d_in[0];
  const float* Wqkv = (const float*)d_in[1];
  const float* bqkv = (const float*)d_in[2];
  const float* Wout = (const float*)d_in[3];
  const float* bout = (const float*)d_in[4];
  float* out = (float*)d_out;
  char* ws = (char*)d_ws;

  // workspace layout (72 MB total)
  unsigned short* xb    = (unsigned short*)ws;                       // 16 MB, M*C bf16
  unsigned short* wqkvt = (unsigned short*)(ws + 16777216);          // 6 MB, [3C][C]
  unsigned short* woutt = (unsigned short*)(ws + 23068672);          // 2 MB, [C][C]
  unsigned short* qkv   = (unsigned short*)(ws + 25165824);          // 48 MB, q|k|vT
  unsigned short* ao    = xb;                                        // reuse xb after QKV GEMM

  f32_to_bf16_kn<<<2048, 256, 0, stream>>>(x, xb, MM * CC);
  transpose_to_bf16<<<dim3(3 * CC / 32, CC / 32), 256, 0, stream>>>(Wqkv, wqkvt, CC, 3 * CC);
  transpose_to_bf16<<<dim3(CC / 32, CC / 32), 256, 0, stream>>>(Wout, woutt, CC, CC);

  gemm128<0><<<dim3(3 * CC / 128, MM / 128), 256, 0, stream>>>(
      xb, wqkvt, bqkv, (void*)qkv, MM, 3 * CC, CC);

  attn_fwd<<<(TT / 64) * BB * HH, 256, 0, stream>>>(
      qkv, qkv + (size_t)MM * CC, qkv + (size_t)2 * MM * CC, ao);

  gemm128<1><<<dim3(CC / 128, MM / 128), 256, 0, stream>>>(
      ao, woutt, bout, (void*)out, MM, CC, CC);
}